// Round 1
// baseline (2382.467 us; speedup 1.0000x reference)
//
#include <hip/hip_runtime.h>
#include <math.h>

// Problem constants: B=4, H=W=64, C=256, DG=8, K=3, cpg=32
// coarse: [4,32,32,256]

// workspace layout (float offsets)
#define OFS_MEAN  0u
#define OFS_GATE  1024u
#define OFS_WB    2048u
#define OFS_CUP   (OFS_WB + 4u*256u*256u)          // 264192
#define OFS_FCAL  (OFS_CUP + 4u*64u*64u*256u)      // 4458496
#define OFS_ALIGN (OFS_FCAL + 4u*64u*64u*256u)     // 8652800
#define OFS_OM    (OFS_ALIGN + 4u*64u*64u*512u)    // 17041408

__global__ void k_zero(float* __restrict__ p){
  p[blockIdx.x*256 + threadIdx.x] = 0.f;
}

// partial GAP over fine: grid (B*8), 256 threads (c), each sums 512 spatial rows
__global__ void k_gap(const float* __restrict__ fine, float* __restrict__ mean){
  int b = blockIdx.x >> 3, chunk = blockIdx.x & 7, c = threadIdx.x;
  const float* p = fine + ((size_t)(b*4096 + chunk*512))*256 + c;
  float s = 0.f;
  for (int i = 0; i < 512; ++i) s += p[i*256];
  atomicAdd(&mean[b*256 + c], s);
}

// attn = sigmoid(mean/4096 @ attend_w); gate = attn + 1
__global__ void k_attn(const float* __restrict__ mean, const float* __restrict__ aw,
                       float* __restrict__ gate){
  __shared__ float m[256];
  int b = blockIdx.x, f = threadIdx.x;
  m[f] = mean[b*256 + f] * (1.f/4096.f);
  __syncthreads();
  float s = 0.f;
  for (int c = 0; c < 256; ++c) s += m[c] * aw[c*256 + f];
  gate[b*256 + f] = 1.f + 1.f/(1.f + expf(-s));
}

// Wb[b][c][f] = gate[b,c] * select_w[c,f]
__global__ void k_foldw(const float* __restrict__ gate, const float* __restrict__ sw,
                        float* __restrict__ wb){
  int b = blockIdx.x >> 8, c = blockIdx.x & 255, f = threadIdx.x;
  wb[((b << 8) + c)*256 + f] = gate[(b << 8) + c] * sw[c*256 + f];
}

// bilinear 2x upsample, half-pixel, clamp-to-edge (== jax.image.resize bilinear)
__global__ void k_up(const float* __restrict__ coarse, float* __restrict__ cup){
  int idx = blockIdx.x*256 + threadIdx.x;           // over B*64*64*64 float4
  int c4 = idx & 63, x = (idx >> 6) & 63, y = (idx >> 12) & 63, b = idx >> 18;
  float fy = 0.5f*y - 0.25f, fx = 0.5f*x - 0.25f;
  float yf = floorf(fy), xf = floorf(fx);
  float wy = fy - yf, wx = fx - xf;
  int r0 = max(0, min(31, (int)yf)), r1 = max(0, min(31, (int)yf + 1));
  int c0 = max(0, min(31, (int)xf)), c1 = max(0, min(31, (int)xf + 1));
  const float4* src = (const float4*)coarse;
  float4 v00 = src[((b*32 + r0)*32 + c0)*64 + c4];
  float4 v01 = src[((b*32 + r0)*32 + c1)*64 + c4];
  float4 v10 = src[((b*32 + r1)*32 + c0)*64 + c4];
  float4 v11 = src[((b*32 + r1)*32 + c1)*64 + c4];
  float w00 = (1.f-wy)*(1.f-wx), w01 = (1.f-wy)*wx, w10 = wy*(1.f-wx), w11 = wy*wx;
  float4 o;
  o.x = v00.x*w00 + v01.x*w01 + v10.x*w10 + v11.x*w11;
  o.y = v00.y*w00 + v01.y*w01 + v10.y*w10 + v11.y*w11;
  o.z = v00.z*w00 + v01.z*w01 + v10.z*w10 + v11.z*w11;
  o.w = v00.w*w00 + v01.w*w01 + v10.w*w10 + v11.w*w11;
  ((float4*)cup)[idx] = o;
}

// fine_cal = fine @ Wb[b]; M-tile 16, N=256 (one f per thread)
__global__ __launch_bounds__(256) void k_fcal(const float* __restrict__ fine,
                                              const float* __restrict__ wb,
                                              float* __restrict__ fcal){
  int m0 = blockIdx.x*16, f = threadIdx.x, b = m0 >> 12;
  const float4* A4 = (const float4*)fine;
  const float* W = wb + b*65536;
  float acc[16];
#pragma unroll
  for (int i = 0; i < 16; ++i) acc[i] = 0.f;
  for (int c4 = 0; c4 < 64; ++c4){
    int k = c4*4;
    float w0 = W[(k+0)*256 + f], w1 = W[(k+1)*256 + f];
    float w2 = W[(k+2)*256 + f], w3 = W[(k+3)*256 + f];
#pragma unroll
    for (int i = 0; i < 16; ++i){
      float4 a = A4[(m0+i)*64 + c4];
      acc[i] += a.x*w0 + a.y*w1 + a.z*w2 + a.w*w3;
    }
  }
  for (int i = 0; i < 16; ++i) fcal[(size_t)(m0+i)*256 + f] = acc[i];
}

// align = concat(fcal, 2*cup) @ offset_w ; N=512 (2 cols/thread), M-tile 16
__global__ __launch_bounds__(256) void k_align(const float* __restrict__ fcal,
                                               const float* __restrict__ cup,
                                               const float* __restrict__ ow,
                                               float* __restrict__ alg){
  int m0 = blockIdx.x*16, f = threadIdx.x;
  float acc0[16], acc1[16];
#pragma unroll
  for (int i = 0; i < 16; ++i){ acc0[i] = 0.f; acc1[i] = 0.f; }
  const float4* A4 = (const float4*)fcal;
  for (int c4 = 0; c4 < 64; ++c4){
    int k = c4*4;
    float w00 = ow[(k+0)*512 + f], w10 = ow[(k+0)*512 + 256 + f];
    float w01 = ow[(k+1)*512 + f], w11 = ow[(k+1)*512 + 256 + f];
    float w02 = ow[(k+2)*512 + f], w12 = ow[(k+2)*512 + 256 + f];
    float w03 = ow[(k+3)*512 + f], w13 = ow[(k+3)*512 + 256 + f];
#pragma unroll
    for (int i = 0; i < 16; ++i){
      float4 a = A4[(m0+i)*64 + c4];
      acc0[i] += a.x*w00 + a.y*w01 + a.z*w02 + a.w*w03;
      acc1[i] += a.x*w10 + a.y*w11 + a.z*w12 + a.w*w13;
    }
  }
  const float4* B4 = (const float4*)cup;
  for (int c4 = 0; c4 < 64; ++c4){
    int k = 256 + c4*4;
    float w00 = 2.f*ow[(k+0)*512 + f], w10 = 2.f*ow[(k+0)*512 + 256 + f];
    float w01 = 2.f*ow[(k+1)*512 + f], w11 = 2.f*ow[(k+1)*512 + 256 + f];
    float w02 = 2.f*ow[(k+2)*512 + f], w12 = 2.f*ow[(k+2)*512 + 256 + f];
    float w03 = 2.f*ow[(k+3)*512 + f], w13 = 2.f*ow[(k+3)*512 + 256 + f];
#pragma unroll
    for (int i = 0; i < 16; ++i){
      float4 a = B4[(m0+i)*64 + c4];
      acc0[i] += a.x*w00 + a.y*w01 + a.z*w02 + a.w*w03;
      acc1[i] += a.x*w10 + a.y*w11 + a.z*w12 + a.w*w13;
    }
  }
  for (int i = 0; i < 16; ++i){
    alg[(size_t)(m0+i)*512 + f] = acc0[i];
    alg[(size_t)(m0+i)*512 + 256 + f] = acc1[i];
  }
}

// om = conv3x3_same(align, om_w) + om_b ; implicit GEMM, M-tile 16 (x-row-aligned), N=216
__global__ __launch_bounds__(256) void k_om(const float* __restrict__ alg,
                                            const float* __restrict__ omw,
                                            const float* __restrict__ omb,
                                            float* __restrict__ om){
  int m0 = blockIdx.x*16;
  int b = m0 >> 12, rem = m0 & 4095, y = rem >> 6, x0 = rem & 63;
  int f = threadIdx.x;
  bool act = f < 216;
  float acc[16];
#pragma unroll
  for (int i = 0; i < 16; ++i) acc[i] = 0.f;
  const float4* A4 = (const float4*)alg;
  for (int ky = 0; ky < 3; ++ky){
    int yy = y + ky - 1;
    if ((unsigned)yy >= 64u) continue;
    int rowbase = ((b*64 + yy)*64)*128;
    for (int c4 = 0; c4 < 128; ++c4){
      float4 av[18];
#pragma unroll
      for (int xp = 0; xp < 18; ++xp){
        int xx = x0 - 1 + xp;
        av[xp] = ((unsigned)xx < 64u) ? A4[rowbase + xx*128 + c4]
                                      : make_float4(0.f, 0.f, 0.f, 0.f);
      }
      if (act){
#pragma unroll
        for (int kx = 0; kx < 3; ++kx){
          const float* wp = omw + (((ky*3 + kx)*512) + c4*4)*216 + f;
          float w0 = wp[0], w1 = wp[216], w2 = wp[432], w3 = wp[648];
#pragma unroll
          for (int i = 0; i < 16; ++i){
            float4 a = av[i + kx];
            acc[i] += a.x*w0 + a.y*w1 + a.z*w2 + a.w*w3;
          }
        }
      }
    }
  }
  if (act){
    float bias = omb[f];
    for (int i = 0; i < 16; ++i) om[(size_t)(m0+i)*216 + f] = acc[i] + bias;
  }
}

// DCNv2: sample (bilinear, zero-pad, mask) into LDS in 3 K-phases, then GEMM.
// M-tile 8; GEMM mapping: m = tid>>5, 8 consecutive f per thread (fg = tid&31)
__global__ __launch_bounds__(256) void k_dcn(const float* __restrict__ cup,
                                             const float* __restrict__ om,
                                             const float* __restrict__ dw,
                                             const float* __restrict__ db,
                                             const float* __restrict__ fcal,
                                             float* __restrict__ out){
  __shared__ float val[8*768];   // 24.5 KB
  int m0 = blockIdx.x*8;
  int b = m0 >> 12, rem = m0 & 4095, y = rem >> 6, x0 = rem & 63;
  int tid = threadIdx.x;
  int cl = tid & 31, unit = tid >> 5;      // staging mapping
  int mI = tid >> 5, fg = tid & 31;        // gemm mapping
  float acc[8];
#pragma unroll
  for (int j = 0; j < 8; ++j) acc[j] = 0.f;
  const float4* dw4 = (const float4*)dw;
  const float* cbase = cup + ((size_t)b*4096)*256;

  for (int ph = 0; ph < 3; ++ph){
    __syncthreads();
    // stage taps k = 3*ph .. 3*ph+2 for 8 rows x 8 groups
    for (int it = 0; it < 24; ++it){
      int u = it*8 + unit;            // 0..191
      int i = u / 24;                 // row 0..7
      int r = u % 24;
      int g = r / 3, kk = r % 3;
      int k = ph*3 + kk;
      const float* omp = om + (size_t)(m0 + i)*216;
      float dy = omp[(g*9 + k)*2 + 0];
      float dx = omp[(g*9 + k)*2 + 1];
      float mv = 1.f / (1.f + expf(-omp[144 + g*9 + k]));
      float yp = (float)(y + k/3 - 1) + dy;
      float xp = (float)(x0 + i + (k%3) - 1) + dx;
      float yf = floorf(yp), xf = floorf(xp);
      float wy = yp - yf, wx = xp - xf;
      int iy = (int)yf, ix = (int)xf;
      const float* base = cbase + g*32 + cl;
      float wA = (1.f-wy)*(1.f-wx), wB = (1.f-wy)*wx, wC = wy*(1.f-wx), wD = wy*wx;
      bool y0ok = (unsigned)iy < 64u, y1ok = (unsigned)(iy+1) < 64u;
      bool x0ok = (unsigned)ix < 64u, x1ok = (unsigned)(ix+1) < 64u;
      float v = 0.f;
      if (y0ok && x0ok) v += wA * base[(iy*64 + ix)*256];
      if (y0ok && x1ok) v += wB * base[(iy*64 + ix + 1)*256];
      if (y1ok && x0ok) v += wC * base[((iy+1)*64 + ix)*256];
      if (y1ok && x1ok) v += wD * base[((iy+1)*64 + ix + 1)*256];
      val[i*768 + kk*256 + g*32 + cl] = v * mv;
    }
    __syncthreads();
    const float* vrow = &val[mI*768];
    for (int kcl4 = 0; kcl4 < 192; ++kcl4){
      float4 a4 = *(const float4*)&vrow[kcl4*4];
      int kcg = ph*768 + kcl4*4;
      float4 w0A = dw4[(kcg+0)*64 + fg*2], w0B = dw4[(kcg+0)*64 + fg*2 + 1];
      float4 w1A = dw4[(kcg+1)*64 + fg*2], w1B = dw4[(kcg+1)*64 + fg*2 + 1];
      float4 w2A = dw4[(kcg+2)*64 + fg*2], w2B = dw4[(kcg+2)*64 + fg*2 + 1];
      float4 w3A = dw4[(kcg+3)*64 + fg*2], w3B = dw4[(kcg+3)*64 + fg*2 + 1];
      acc[0] += a4.x*w0A.x + a4.y*w1A.x + a4.z*w2A.x + a4.w*w3A.x;
      acc[1] += a4.x*w0A.y + a4.y*w1A.y + a4.z*w2A.y + a4.w*w3A.y;
      acc[2] += a4.x*w0A.z + a4.y*w1A.z + a4.z*w2A.z + a4.w*w3A.z;
      acc[3] += a4.x*w0A.w + a4.y*w1A.w + a4.z*w2A.w + a4.w*w3A.w;
      acc[4] += a4.x*w0B.x + a4.y*w1B.x + a4.z*w2B.x + a4.w*w3B.x;
      acc[5] += a4.x*w0B.y + a4.y*w1B.y + a4.z*w2B.y + a4.w*w3B.y;
      acc[6] += a4.x*w0B.z + a4.y*w1B.z + a4.z*w2B.z + a4.w*w3B.z;
      acc[7] += a4.x*w0B.w + a4.y*w1B.w + a4.z*w2B.w + a4.w*w3B.w;
    }
  }
  // epilogue: relu(acc + bias) + fine_cal
  int m = m0 + mI;
  const float4* db4 = (const float4*)db;
  const float4* fc4 = (const float4*)fcal;
  float4 bA = db4[fg*2], bB = db4[fg*2 + 1];
  float4 fA = fc4[(size_t)m*64 + fg*2], fB = fc4[(size_t)m*64 + fg*2 + 1];
  float4 oA, oB;
  oA.x = fmaxf(acc[0] + bA.x, 0.f) + fA.x;
  oA.y = fmaxf(acc[1] + bA.y, 0.f) + fA.y;
  oA.z = fmaxf(acc[2] + bA.z, 0.f) + fA.z;
  oA.w = fmaxf(acc[3] + bA.w, 0.f) + fA.w;
  oB.x = fmaxf(acc[4] + bB.x, 0.f) + fB.x;
  oB.y = fmaxf(acc[5] + bB.y, 0.f) + fB.y;
  oB.z = fmaxf(acc[6] + bB.z, 0.f) + fB.z;
  oB.w = fmaxf(acc[7] + bB.w, 0.f) + fB.w;
  ((float4*)out)[(size_t)m*64 + fg*2] = oA;
  ((float4*)out)[(size_t)m*64 + fg*2 + 1] = oB;
}

extern "C" void kernel_launch(void* const* d_in, const int* in_sizes, int n_in,
                              void* d_out, int out_size, void* d_ws, size_t ws_size,
                              hipStream_t stream){
  const float* fine     = (const float*)d_in[0];
  const float* coarse   = (const float*)d_in[1];
  const float* attend_w = (const float*)d_in[2];
  const float* select_w = (const float*)d_in[3];
  const float* offset_w = (const float*)d_in[4];
  const float* om_w     = (const float*)d_in[5];
  const float* om_b     = (const float*)d_in[6];
  const float* dcn_w    = (const float*)d_in[7];
  const float* dcn_b    = (const float*)d_in[8];
  float* out = (float*)d_out;
  float* ws  = (float*)d_ws;

  float* mean = ws + OFS_MEAN;
  float* gate = ws + OFS_GATE;
  float* wb   = ws + OFS_WB;
  float* cup  = ws + OFS_CUP;
  float* fcal = ws + OFS_FCAL;
  float* alg  = ws + OFS_ALIGN;
  float* om   = ws + OFS_OM;

  hipLaunchKernelGGL(k_zero,  dim3(4),    dim3(256), 0, stream, mean);
  hipLaunchKernelGGL(k_gap,   dim3(32),   dim3(256), 0, stream, fine, mean);
  hipLaunchKernelGGL(k_attn,  dim3(4),    dim3(256), 0, stream, mean, attend_w, gate);
  hipLaunchKernelGGL(k_foldw, dim3(1024), dim3(256), 0, stream, gate, select_w, wb);
  hipLaunchKernelGGL(k_up,    dim3(4096), dim3(256), 0, stream, coarse, cup);
  hipLaunchKernelGGL(k_fcal,  dim3(1024), dim3(256), 0, stream, fine, wb, fcal);
  hipLaunchKernelGGL(k_align, dim3(1024), dim3(256), 0, stream, fcal, cup, offset_w, alg);
  hipLaunchKernelGGL(k_om,    dim3(1024), dim3(256), 0, stream, alg, om_w, om_b, om);
  hipLaunchKernelGGL(k_dcn,   dim3(2048), dim3(256), 0, stream, cup, om, dcn_w, dcn_b, fcal, out);
  (void)in_sizes; (void)n_in; (void)out_size; (void)ws_size;
}

// Round 2
// 624.723 us; speedup vs baseline: 3.8136x; 3.8136x over previous
//
#include <hip/hip_runtime.h>
#include <math.h>

// B=4, H=W=64, C=256, DG=8, K=3, cpg=32; coarse: [4,32,32,256]

typedef __attribute__((ext_vector_type(8))) short bf16x8;
typedef __attribute__((ext_vector_type(4))) float f32x4;
#define MFMA16(a,b,c) __builtin_amdgcn_mfma_f32_16x16x32_bf16(a,b,c,0,0,0)

__device__ inline short f2b(float x){
  union { float f; unsigned u; } v; v.f = x;
  unsigned r = v.u + 0x7FFFu + ((v.u >> 16) & 1u);
  return (short)(r >> 16);
}

// workspace layout (float offsets)
#define OFS_MEAN  0u
#define OFS_GATE  1024u
#define OFS_WB    2048u
#define OFS_CUP   264192u
#define OFS_FCAL  4458496u
#define OFS_ALGB  8652800u     // bf16 [16384][512]
#define OFS_OM    12847104u    // f32  [16384][216]
#define OFS_DWB   16386048u    // bf16 frag [72][16][64][8]
#define OFS_OMWB  16680960u    // bf16 frag [144][16][64][8]

__global__ void k_zero(float* __restrict__ p){
  p[blockIdx.x*256 + threadIdx.x] = 0.f;
}

__global__ void k_gap(const float* __restrict__ fine, float* __restrict__ mean){
  int b = blockIdx.x >> 3, chunk = blockIdx.x & 7, c = threadIdx.x;
  const float* p = fine + ((size_t)(b*4096 + chunk*512))*256 + c;
  float s = 0.f;
  for (int i = 0; i < 512; ++i) s += p[i*256];
  atomicAdd(&mean[b*256 + c], s);
}

__global__ void k_attn(const float* __restrict__ mean, const float* __restrict__ aw,
                       float* __restrict__ gate){
  __shared__ float m[256];
  int b = blockIdx.x, f = threadIdx.x;
  m[f] = mean[b*256 + f] * (1.f/4096.f);
  __syncthreads();
  float s = 0.f;
  for (int c = 0; c < 256; ++c) s += m[c] * aw[c*256 + f];
  gate[b*256 + f] = 1.f + 1.f/(1.f + expf(-s));
}

__global__ void k_foldw(const float* __restrict__ gate, const float* __restrict__ sw,
                        float* __restrict__ wb){
  int b = blockIdx.x >> 8, c = blockIdx.x & 255, f = threadIdx.x;
  wb[((b << 8) + c)*256 + f] = gate[(b << 8) + c] * sw[c*256 + f];
}

__global__ void k_up(const float* __restrict__ coarse, float* __restrict__ cup){
  int idx = blockIdx.x*256 + threadIdx.x;
  int c4 = idx & 63, x = (idx >> 6) & 63, y = (idx >> 12) & 63, b = idx >> 18;
  float fy = 0.5f*y - 0.25f, fx = 0.5f*x - 0.25f;
  float yf = floorf(fy), xf = floorf(fx);
  float wy = fy - yf, wx = fx - xf;
  int r0 = max(0, min(31, (int)yf)), r1 = max(0, min(31, (int)yf + 1));
  int c0 = max(0, min(31, (int)xf)), c1 = max(0, min(31, (int)xf + 1));
  const float4* src = (const float4*)coarse;
  float4 v00 = src[((b*32 + r0)*32 + c0)*64 + c4];
  float4 v01 = src[((b*32 + r0)*32 + c1)*64 + c4];
  float4 v10 = src[((b*32 + r1)*32 + c0)*64 + c4];
  float4 v11 = src[((b*32 + r1)*32 + c1)*64 + c4];
  float w00 = (1.f-wy)*(1.f-wx), w01 = (1.f-wy)*wx, w10 = wy*(1.f-wx), w11 = wy*wx;
  float4 o;
  o.x = v00.x*w00 + v01.x*w01 + v10.x*w10 + v11.x*w11;
  o.y = v00.y*w00 + v01.y*w01 + v10.y*w10 + v11.y*w11;
  o.z = v00.z*w00 + v01.z*w01 + v10.z*w10 + v11.z*w11;
  o.w = v00.w*w00 + v01.w*w01 + v10.w*w10 + v11.w*w11;
  ((float4*)cup)[idx] = o;
}

__global__ __launch_bounds__(256) void k_fcal(const float* __restrict__ fine,
                                              const float* __restrict__ wb,
                                              float* __restrict__ fcal){
  int m0 = blockIdx.x*16, f = threadIdx.x, b = m0 >> 12;
  const float4* A4 = (const float4*)fine;
  const float* W = wb + b*65536;
  float acc[16];
#pragma unroll
  for (int i = 0; i < 16; ++i) acc[i] = 0.f;
  for (int c4 = 0; c4 < 64; ++c4){
    int k = c4*4;
    float w0 = W[(k+0)*256 + f], w1 = W[(k+1)*256 + f];
    float w2 = W[(k+2)*256 + f], w3 = W[(k+3)*256 + f];
#pragma unroll
    for (int i = 0; i < 16; ++i){
      float4 a = A4[(m0+i)*64 + c4];
      acc[i] += a.x*w0 + a.y*w1 + a.z*w2 + a.w*w3;
    }
  }
  for (int i = 0; i < 16; ++i) fcal[(size_t)(m0+i)*256 + f] = acc[i];
}

// align GEMM -> bf16 output [16384][512]
__global__ __launch_bounds__(256) void k_align(const float* __restrict__ fcal,
                                               const float* __restrict__ cup,
                                               const float* __restrict__ ow,
                                               short* __restrict__ algb){
  int m0 = blockIdx.x*16, f = threadIdx.x;
  float acc0[16], acc1[16];
#pragma unroll
  for (int i = 0; i < 16; ++i){ acc0[i] = 0.f; acc1[i] = 0.f; }
  const float4* A4 = (const float4*)fcal;
  for (int c4 = 0; c4 < 64; ++c4){
    int k = c4*4;
    float w00 = ow[(k+0)*512 + f], w10 = ow[(k+0)*512 + 256 + f];
    float w01 = ow[(k+1)*512 + f], w11 = ow[(k+1)*512 + 256 + f];
    float w02 = ow[(k+2)*512 + f], w12 = ow[(k+2)*512 + 256 + f];
    float w03 = ow[(k+3)*512 + f], w13 = ow[(k+3)*512 + 256 + f];
#pragma unroll
    for (int i = 0; i < 16; ++i){
      float4 a = A4[(m0+i)*64 + c4];
      acc0[i] += a.x*w00 + a.y*w01 + a.z*w02 + a.w*w03;
      acc1[i] += a.x*w10 + a.y*w11 + a.z*w12 + a.w*w13;
    }
  }
  const float4* B4 = (const float4*)cup;
  for (int c4 = 0; c4 < 64; ++c4){
    int k = 256 + c4*4;
    float w00 = 2.f*ow[(k+0)*512 + f], w10 = 2.f*ow[(k+0)*512 + 256 + f];
    float w01 = 2.f*ow[(k+1)*512 + f], w11 = 2.f*ow[(k+1)*512 + 256 + f];
    float w02 = 2.f*ow[(k+2)*512 + f], w12 = 2.f*ow[(k+2)*512 + 256 + f];
    float w03 = 2.f*ow[(k+3)*512 + f], w13 = 2.f*ow[(k+3)*512 + 256 + f];
#pragma unroll
    for (int i = 0; i < 16; ++i){
      float4 a = B4[(m0+i)*64 + c4];
      acc0[i] += a.x*w00 + a.y*w01 + a.z*w02 + a.w*w03;
      acc1[i] += a.x*w10 + a.y*w11 + a.z*w12 + a.w*w13;
    }
  }
  for (int i = 0; i < 16; ++i){
    algb[(size_t)(m0+i)*512 + f] = f2b(acc0[i]);
    algb[(size_t)(m0+i)*512 + 256 + f] = f2b(acc1[i]);
  }
}

// dcn_w -> B-frag bf16: dwb[((ksg*16+nt)*64+l)*8+j]; k = ksg*32+(l>>4)*8+j, n = nt*16+(l&15)
__global__ void k_cvt_dwb(const float* __restrict__ dw, short* __restrict__ dwb){
  int t = blockIdx.x*256 + threadIdx.x;          // 73728
  int l = t & 63, nt = (t >> 6) & 15, ksg = t >> 10;
  int n = nt*16 + (l & 15);
  int kb = ksg*32 + (l >> 4)*8;
  bf16x8 o;
#pragma unroll
  for (int j = 0; j < 8; ++j) o[j] = f2b(dw[(size_t)(kb + j)*256 + n]);
  ((bf16x8*)dwb)[t] = o;
}

// om_w -> B-frag bf16, N padded 216->256
__global__ void k_cvt_omwb(const float* __restrict__ omw, short* __restrict__ omwb){
  int t = blockIdx.x*256 + threadIdx.x;          // 147456
  int l = t & 63, nt = (t >> 6) & 15, ksg = t >> 10;
  int n = nt*16 + (l & 15);
  int kb = ksg*32 + (l >> 4)*8;
  bf16x8 o;
#pragma unroll
  for (int j = 0; j < 8; ++j)
    o[j] = (n < 216) ? f2b(omw[(size_t)(kb + j)*216 + n]) : (short)0;
  ((bf16x8*)omwb)[t] = o;
}

// om conv3x3 as MFMA implicit GEMM. M-tile 32, N padded 256, phase per ky.
#define XST 520   // LDS x-row stride (shorts): 512+8, 16B-aligned
__global__ __launch_bounds__(256) void k_om(const short* __restrict__ algb,
                                            const short* __restrict__ omwb,
                                            const float* __restrict__ omb,
                                            float* __restrict__ om){
  __shared__ short xbuf[34*XST];
  int m0 = blockIdx.x*32;
  int b = m0 >> 12, y = (m0 & 4095) >> 6, x0 = m0 & 63;
  int tid = threadIdx.x;
  int lane = tid & 63, wave = tid >> 6;
  int arow = lane & 15, aquad = lane >> 4;
  f32x4 acc[2][4];
#pragma unroll
  for (int s = 0; s < 2; ++s)
#pragma unroll
    for (int t = 0; t < 4; ++t) acc[s][t] = (f32x4){0.f,0.f,0.f,0.f};
  const bf16x8* W8 = (const bf16x8*)omwb;
  for (int ky = 0; ky < 3; ++ky){
    int yy = y + ky - 1;
    if ((unsigned)yy >= 64u) continue;           // block-uniform
    __syncthreads();
    const short* srow = algb + (size_t)((b*64 + yy)*64)*512;
    for (int it = 0; it < 9; ++it){
      int idx = it*256 + tid;                    // < 2176
      if (idx < 2176){
        int xx = idx >> 6, l8 = idx & 63;
        int gx = x0 - 1 + xx;
        bf16x8 v = (bf16x8){0,0,0,0,0,0,0,0};
        if ((unsigned)gx < 64u) v = *(const bf16x8*)(srow + (size_t)gx*512 + l8*8);
        *(bf16x8*)&xbuf[xx*XST + l8*8] = v;
      }
    }
    __syncthreads();
    for (int ks = 0; ks < 48; ++ks){
      int kl = ks*32 + aquad*8;
      int kx = kl >> 9, cc = kl & 511;
      bf16x8 a0 = *(const bf16x8*)&xbuf[(arow + kx)*XST + cc];
      bf16x8 a1 = *(const bf16x8*)&xbuf[(16 + arow + kx)*XST + cc];
      const bf16x8* wp = W8 + ((size_t)((ky*48 + ks)*16 + wave*4))*64 + lane;
#pragma unroll
      for (int t = 0; t < 4; ++t){
        bf16x8 bw = wp[t*64];
        acc[0][t] = MFMA16(a0, bw, acc[0][t]);
        acc[1][t] = MFMA16(a1, bw, acc[1][t]);
      }
    }
  }
#pragma unroll
  for (int t = 0; t < 4; ++t){
    int f = wave*64 + t*16 + (lane & 15);
    if (f < 216){
      float bias = omb[f];
#pragma unroll
      for (int s = 0; s < 2; ++s){
#pragma unroll
        for (int r = 0; r < 4; ++r){
          int m = m0 + s*16 + (lane >> 4)*4 + r;
          om[(size_t)m*216 + f] = acc[s][t][r] + bias;
        }
      }
    }
  }
}

// DCNv2: sample -> bf16 LDS (3-tap phases), MFMA GEMM. M-tile 16.
#define VST 776   // LDS val row stride (shorts): 768+8, 16B-aligned
__global__ __launch_bounds__(256) void k_dcn(const float* __restrict__ cup,
                                             const float* __restrict__ om,
                                             const short* __restrict__ dwb,
                                             const float* __restrict__ db,
                                             const float* __restrict__ fcal,
                                             float* __restrict__ out){
  __shared__ short valb[16*VST];   // 24832 B
  int m0 = blockIdx.x*16;
  int b = m0 >> 12, y = (m0 & 4095) >> 6, x0 = m0 & 63;
  int tid = threadIdx.x;
  int lane = tid & 63, wave = tid >> 6;
  int cl = tid & 31, unit = tid >> 5;
  int arow = lane & 15, aquad = lane >> 4;
  f32x4 acc[4];
#pragma unroll
  for (int t = 0; t < 4; ++t) acc[t] = (f32x4){0.f,0.f,0.f,0.f};
  const float* cbase = cup + (size_t)b*4096*256;
  const bf16x8* W8 = (const bf16x8*)dwb;

  for (int ph = 0; ph < 3; ++ph){
    __syncthreads();
    for (int it = 0; it < 48; ++it){
      int u = it*8 + unit;
      int i = u / 24; int r = u - i*24; int g = r / 3; int kk = r - g*3;
      const float* omp = om + (size_t)(m0 + i)*216;
      int k = ph*3 + kk;
      float dy = omp[(g*9 + k)*2 + 0];
      float dx = omp[(g*9 + k)*2 + 1];
      float mv = 1.f / (1.f + expf(-omp[144 + g*9 + k]));
      float yp = (float)(y + ph - 1) + dy;
      float xp = (float)(x0 + i + kk - 1) + dx;
      float yf = floorf(yp), xf = floorf(xp);
      float wy = yp - yf, wx = xp - xf;
      int iy = (int)yf, ix = (int)xf;
      const float* base = cbase + g*32 + cl;
      float wA = (1.f-wy)*(1.f-wx), wB = (1.f-wy)*wx, wC = wy*(1.f-wx), wD = wy*wx;
      bool y0ok = (unsigned)iy < 64u, y1ok = (unsigned)(iy+1) < 64u;
      bool x0ok = (unsigned)ix < 64u, x1ok = (unsigned)(ix+1) < 64u;
      float v = 0.f;
      if (y0ok && x0ok) v += wA * base[(iy*64 + ix)*256];
      if (y0ok && x1ok) v += wB * base[(iy*64 + ix + 1)*256];
      if (y1ok && x0ok) v += wC * base[((iy+1)*64 + ix)*256];
      if (y1ok && x1ok) v += wD * base[((iy+1)*64 + ix + 1)*256];
      valb[i*VST + kk*256 + g*32 + cl] = f2b(v * mv);
    }
    __syncthreads();
    for (int ks = 0; ks < 24; ++ks){
      bf16x8 a = *(const bf16x8*)&valb[arow*VST + ks*32 + aquad*8];
      const bf16x8* wp = W8 + ((size_t)((ph*24 + ks)*16 + wave*4))*64 + lane;
#pragma unroll
      for (int t = 0; t < 4; ++t)
        acc[t] = MFMA16(a, wp[t*64], acc[t]);
    }
  }
#pragma unroll
  for (int t = 0; t < 4; ++t){
    int f = wave*64 + t*16 + (lane & 15);
    float bias = db[f];
#pragma unroll
    for (int r = 0; r < 4; ++r){
      int m = m0 + (lane >> 4)*4 + r;
      out[(size_t)m*256 + f] = fmaxf(acc[t][r] + bias, 0.f) + fcal[(size_t)m*256 + f];
    }
  }
}

extern "C" void kernel_launch(void* const* d_in, const int* in_sizes, int n_in,
                              void* d_out, int out_size, void* d_ws, size_t ws_size,
                              hipStream_t stream){
  const float* fine     = (const float*)d_in[0];
  const float* coarse   = (const float*)d_in[1];
  const float* attend_w = (const float*)d_in[2];
  const float* select_w = (const float*)d_in[3];
  const float* offset_w = (const float*)d_in[4];
  const float* om_w     = (const float*)d_in[5];
  const float* om_b     = (const float*)d_in[6];
  const float* dcn_w    = (const float*)d_in[7];
  const float* dcn_b    = (const float*)d_in[8];
  float* out = (float*)d_out;
  float* ws  = (float*)d_ws;

  float* mean = ws + OFS_MEAN;
  float* gate = ws + OFS_GATE;
  float* wb   = ws + OFS_WB;
  float* cup  = ws + OFS_CUP;
  float* fcal = ws + OFS_FCAL;
  short* algb = (short*)(ws + OFS_ALGB);
  float* om   = ws + OFS_OM;
  short* dwb  = (short*)(ws + OFS_DWB);
  short* omwb = (short*)(ws + OFS_OMWB);

  hipLaunchKernelGGL(k_zero,     dim3(4),    dim3(256), 0, stream, mean);
  hipLaunchKernelGGL(k_cvt_dwb,  dim3(288),  dim3(256), 0, stream, dcn_w, dwb);
  hipLaunchKernelGGL(k_cvt_omwb, dim3(576),  dim3(256), 0, stream, om_w, omwb);
  hipLaunchKernelGGL(k_gap,      dim3(32),   dim3(256), 0, stream, fine, mean);
  hipLaunchKernelGGL(k_attn,     dim3(4),    dim3(256), 0, stream, mean, attend_w, gate);
  hipLaunchKernelGGL(k_foldw,    dim3(1024), dim3(256), 0, stream, gate, select_w, wb);
  hipLaunchKernelGGL(k_up,       dim3(4096), dim3(256), 0, stream, coarse, cup);
  hipLaunchKernelGGL(k_fcal,     dim3(1024), dim3(256), 0, stream, fine, wb, fcal);
  hipLaunchKernelGGL(k_align,    dim3(1024), dim3(256), 0, stream, fcal, cup, offset_w, algb);
  hipLaunchKernelGGL(k_om,       dim3(512),  dim3(256), 0, stream, algb, omwb, om_b, om);
  hipLaunchKernelGGL(k_dcn,      dim3(1024), dim3(256), 0, stream, cup, om, dwb, dcn_b, fcal, out);
  (void)in_sizes; (void)n_in; (void)out_size; (void)ws_size;
}

// Round 5
// 454.652 us; speedup vs baseline: 5.2402x; 1.3741x over previous
//
#include <hip/hip_runtime.h>
#include <math.h>

// B=4, H=W=64, C=256, DG=8, K=3, cpg=32; coarse: [4,32,32,256]

typedef __attribute__((ext_vector_type(8))) short bf16x8;
typedef __attribute__((ext_vector_type(4))) float f32x4;
#define MFMA16(a,b,c) __builtin_amdgcn_mfma_f32_16x16x32_bf16(a,b,c,0,0,0)

__device__ inline short f2b(float x){
  union { float f; unsigned u; } v; v.f = x;
  unsigned r = v.u + 0x7FFFu + ((v.u >> 16) & 1u);
  return (short)(r >> 16);
}

// workspace layout (float offsets)
#define OFS_MEAN  0u
#define OFS_GATE  1024u
#define OFS_WB    2048u
#define OFS_CUP   264192u
#define OFS_FCAL  4458496u
#define OFS_ALGB  8652800u     // bf16 [16384][512]
#define OFS_OM    12847104u    // f32  [16384][216]
#define OFS_DWB   16386048u    // bf16 frag [72][16][64][8]
#define OFS_OMWB  16680960u    // bf16 frag [144][16][64][8]

__global__ void k_zero(float* __restrict__ p){
  p[blockIdx.x*256 + threadIdx.x] = 0.f;
}

__global__ void k_gap(const float* __restrict__ fine, float* __restrict__ mean){
  int b = blockIdx.x >> 3, chunk = blockIdx.x & 7, c = threadIdx.x;
  const float* p = fine + ((size_t)(b*4096 + chunk*512))*256 + c;
  float s = 0.f;
  for (int i = 0; i < 512; ++i) s += p[i*256];
  atomicAdd(&mean[b*256 + c], s);
}

__global__ void k_attn(const float* __restrict__ mean, const float* __restrict__ aw,
                       float* __restrict__ gate){
  __shared__ float m[256];
  int b = blockIdx.x, f = threadIdx.x;
  m[f] = mean[b*256 + f] * (1.f/4096.f);
  __syncthreads();
  float s = 0.f;
  for (int c = 0; c < 256; ++c) s += m[c] * aw[c*256 + f];
  gate[b*256 + f] = 1.f + 1.f/(1.f + expf(-s));
}

// Wb[b][c][f] = gate[b,c] * select_w[c,f]   (fp32 — upstream of offsets)
__global__ void k_foldw(const float* __restrict__ gate, const float* __restrict__ sw,
                        float* __restrict__ wb){
  int b = blockIdx.x >> 8, c = blockIdx.x & 255, f = threadIdx.x;
  wb[((b << 8) + c)*256 + f] = gate[(b << 8) + c] * sw[c*256 + f];
}

__global__ void k_up(const float* __restrict__ coarse, float* __restrict__ cup){
  int idx = blockIdx.x*256 + threadIdx.x;
  int c4 = idx & 63, x = (idx >> 6) & 63, y = (idx >> 12) & 63, b = idx >> 18;
  float fy = 0.5f*y - 0.25f, fx = 0.5f*x - 0.25f;
  float yf = floorf(fy), xf = floorf(fx);
  float wy = fy - yf, wx = fx - xf;
  int r0 = max(0, min(31, (int)yf)), r1 = max(0, min(31, (int)yf + 1));
  int c0 = max(0, min(31, (int)xf)), c1 = max(0, min(31, (int)xf + 1));
  const float4* src = (const float4*)coarse;
  float4 v00 = src[((b*32 + r0)*32 + c0)*64 + c4];
  float4 v01 = src[((b*32 + r0)*32 + c1)*64 + c4];
  float4 v10 = src[((b*32 + r1)*32 + c0)*64 + c4];
  float4 v11 = src[((b*32 + r1)*32 + c1)*64 + c4];
  float w00 = (1.f-wy)*(1.f-wx), w01 = (1.f-wy)*wx, w10 = wy*(1.f-wx), w11 = wy*wx;
  float4 o;
  o.x = v00.x*w00 + v01.x*w01 + v10.x*w10 + v11.x*w11;
  o.y = v00.y*w00 + v01.y*w01 + v10.y*w10 + v11.y*w11;
  o.z = v00.z*w00 + v01.z*w01 + v10.z*w10 + v11.z*w11;
  o.w = v00.w*w00 + v01.w*w01 + v10.w*w10 + v11.w*w11;
  ((float4*)cup)[idx] = o;
}

// fine_cal = fine @ Wb[b]; fp32, M-tile 16
__global__ __launch_bounds__(256) void k_fcal(const float* __restrict__ fine,
                                              const float* __restrict__ wb,
                                              float* __restrict__ fcal){
  int m0 = blockIdx.x*16, f = threadIdx.x, b = m0 >> 12;
  const float4* A4 = (const float4*)fine;
  const float* W = wb + b*65536;
  float acc[16];
#pragma unroll
  for (int i = 0; i < 16; ++i) acc[i] = 0.f;
  for (int c4 = 0; c4 < 64; ++c4){
    int k = c4*4;
    float w0 = W[(k+0)*256 + f], w1 = W[(k+1)*256 + f];
    float w2 = W[(k+2)*256 + f], w3 = W[(k+3)*256 + f];
#pragma unroll
    for (int i = 0; i < 16; ++i){
      float4 a = A4[(m0+i)*64 + c4];
      acc[i] += a.x*w0 + a.y*w1 + a.z*w2 + a.w*w3;
    }
  }
  for (int i = 0; i < 16; ++i) fcal[(size_t)(m0+i)*256 + f] = acc[i];
}

// align = concat(fcal, 2*cup) @ offset_w ; fp32 compute, bf16 output
__global__ __launch_bounds__(256) void k_align(const float* __restrict__ fcal,
                                               const float* __restrict__ cup,
                                               const float* __restrict__ ow,
                                               short* __restrict__ algb){
  int m0 = blockIdx.x*16, f = threadIdx.x;
  float acc0[16], acc1[16];
#pragma unroll
  for (int i = 0; i < 16; ++i){ acc0[i] = 0.f; acc1[i] = 0.f; }
  const float4* A4 = (const float4*)fcal;
  for (int c4 = 0; c4 < 64; ++c4){
    int k = c4*4;
    float w00 = ow[(k+0)*512 + f], w10 = ow[(k+0)*512 + 256 + f];
    float w01 = ow[(k+1)*512 + f], w11 = ow[(k+1)*512 + 256 + f];
    float w02 = ow[(k+2)*512 + f], w12 = ow[(k+2)*512 + 256 + f];
    float w03 = ow[(k+3)*512 + f], w13 = ow[(k+3)*512 + 256 + f];
#pragma unroll
    for (int i = 0; i < 16; ++i){
      float4 a = A4[(m0+i)*64 + c4];
      acc0[i] += a.x*w00 + a.y*w01 + a.z*w02 + a.w*w03;
      acc1[i] += a.x*w10 + a.y*w11 + a.z*w12 + a.w*w13;
    }
  }
  const float4* B4 = (const float4*)cup;
  for (int c4 = 0; c4 < 64; ++c4){
    int k = 256 + c4*4;
    float w00 = 2.f*ow[(k+0)*512 + f], w10 = 2.f*ow[(k+0)*512 + 256 + f];
    float w01 = 2.f*ow[(k+1)*512 + f], w11 = 2.f*ow[(k+1)*512 + 256 + f];
    float w02 = 2.f*ow[(k+2)*512 + f], w12 = 2.f*ow[(k+2)*512 + 256 + f];
    float w03 = 2.f*ow[(k+3)*512 + f], w13 = 2.f*ow[(k+3)*512 + 256 + f];
#pragma unroll
    for (int i = 0; i < 16; ++i){
      float4 a = B4[(m0+i)*64 + c4];
      acc0[i] += a.x*w00 + a.y*w01 + a.z*w02 + a.w*w03;
      acc1[i] += a.x*w10 + a.y*w11 + a.z*w12 + a.w*w13;
    }
  }
  for (int i = 0; i < 16; ++i){
    algb[(size_t)(m0+i)*512 + f] = f2b(acc0[i]);
    algb[(size_t)(m0+i)*512 + 256 + f] = f2b(acc1[i]);
  }
}

// dcn_w -> B-frag bf16
__global__ void k_cvt_dwb(const float* __restrict__ dw, short* __restrict__ dwb){
  int t = blockIdx.x*256 + threadIdx.x;          // 73728
  int l = t & 63, nt = (t >> 6) & 15, ksg = t >> 10;
  int n = nt*16 + (l & 15);
  int kb = ksg*32 + (l >> 4)*8;
  bf16x8 o;
#pragma unroll
  for (int j = 0; j < 8; ++j) o[j] = f2b(dw[(size_t)(kb + j)*256 + n]);
  ((bf16x8*)dwb)[t] = o;
}

// om_w -> B-frag bf16, N padded 216->256
__global__ void k_cvt_omwb(const float* __restrict__ omw, short* __restrict__ omwb){
  int t = blockIdx.x*256 + threadIdx.x;          // 147456
  int l = t & 63, nt = (t >> 6) & 15, ksg = t >> 10;
  int n = nt*16 + (l & 15);
  int kb = ksg*32 + (l >> 4)*8;
  bf16x8 o;
#pragma unroll
  for (int j = 0; j < 8; ++j)
    o[j] = (n < 216) ? f2b(omw[(size_t)(kb + j)*216 + n]) : (short)0;
  ((bf16x8*)omwb)[t] = o;
}

// om conv3x3 as MFMA implicit GEMM. M-tile 32, N padded 256, phase per ky.
#define XST 520
__global__ __launch_bounds__(256) void k_om(const short* __restrict__ algb,
                                            const short* __restrict__ omwb,
                                            const float* __restrict__ omb,
                                            float* __restrict__ om){
  __shared__ short xbuf[34*XST];
  int m0 = blockIdx.x*32;
  int b = m0 >> 12, y = (m0 & 4095) >> 6, x0 = m0 & 63;
  int tid = threadIdx.x;
  int lane = tid & 63, wave = tid >> 6;
  int arow = lane & 15, aquad = lane >> 4;
  f32x4 acc[2][4];
#pragma unroll
  for (int s = 0; s < 2; ++s)
#pragma unroll
    for (int t = 0; t < 4; ++t) acc[s][t] = (f32x4){0.f,0.f,0.f,0.f};
  const bf16x8* W8 = (const bf16x8*)omwb;
  for (int ky = 0; ky < 3; ++ky){
    int yy = y + ky - 1;
    if ((unsigned)yy >= 64u) continue;           // block-uniform
    __syncthreads();
    const short* srow = algb + (size_t)((b*64 + yy)*64)*512;
    for (int it = 0; it < 9; ++it){
      int idx = it*256 + tid;
      if (idx < 2176){
        int xx = idx >> 6, l8 = idx & 63;
        int gx = x0 - 1 + xx;
        bf16x8 v = (bf16x8){0,0,0,0,0,0,0,0};
        if ((unsigned)gx < 64u) v = *(const bf16x8*)(srow + (size_t)gx*512 + l8*8);
        *(bf16x8*)&xbuf[xx*XST + l8*8] = v;
      }
    }
    __syncthreads();
    for (int ks = 0; ks < 48; ++ks){
      int kl = ks*32 + aquad*8;
      int kx = kl >> 9, cc = kl & 511;
      bf16x8 a0 = *(const bf16x8*)&xbuf[(arow + kx)*XST + cc];
      bf16x8 a1 = *(const bf16x8*)&xbuf[(16 + arow + kx)*XST + cc];
      const bf16x8* wp = W8 + ((size_t)((ky*48 + ks)*16 + wave*4))*64 + lane;
#pragma unroll
      for (int t = 0; t < 4; ++t){
        bf16x8 bw = wp[t*64];
        acc[0][t] = MFMA16(a0, bw, acc[0][t]);
        acc[1][t] = MFMA16(a1, bw, acc[1][t]);
      }
    }
  }
#pragma unroll
  for (int t = 0; t < 4; ++t){
    int f = wave*64 + t*16 + (lane & 15);
    if (f < 216){
      float bias = omb[f];
#pragma unroll
      for (int s = 0; s < 2; ++s)
#pragma unroll
        for (int r = 0; r < 4; ++r){
          int m = m0 + s*16 + (lane >> 4)*4 + r;
          om[(size_t)m*216 + f] = acc[s][t][r] + bias;
        }
    }
  }
}

// DCNv2: staging by 8-lane units (params in-register, float4 channel gather),
// then MFMA GEMM. M-tile 16. Round-2 math verbatim; no param LDS round-trip.
#define VST 776
__global__ __launch_bounds__(256) void k_dcn(const float* __restrict__ cup,
                                             const float* __restrict__ om,
                                             const short* __restrict__ dwb,
                                             const float* __restrict__ db,
                                             const float* __restrict__ fcal,
                                             float* __restrict__ out){
  __shared__ short valb[16*VST];   // 24832 B
  int m0 = blockIdx.x*16;
  int b = m0 >> 12, y = (m0 & 4095) >> 6, x0 = m0 & 63;
  int tid = threadIdx.x;
  int lane = tid & 63, wave = tid >> 6;
  int unit = tid >> 3, lane8 = tid & 7;    // 32 units x 8 lanes
  int arow = lane & 15, aquad = lane >> 4;
  f32x4 acc[4];
#pragma unroll
  for (int t = 0; t < 4; ++t) acc[t] = (f32x4){0.f,0.f,0.f,0.f};
  const float4* cb4 = (const float4*)(cup + (size_t)b*4096*256);
  const bf16x8* W8 = (const bf16x8*)dwb;

  for (int ph = 0; ph < 3; ++ph){
    __syncthreads();
    // stage 384 samples (16 rows x 8 g x 3 taps); each unit: 12 samples
    for (int j = 0; j < 12; ++j){
      int u = j*32 + unit;
      int i = u / 24; int r = u - i*24; int g = r / 3; int kk = r - g*3;
      const float* omp = om + (size_t)(m0 + i)*216;
      int k = ph*3 + kk;
      float dy = omp[(g*9 + k)*2 + 0];
      float dx = omp[(g*9 + k)*2 + 1];
      float mv = 1.f / (1.f + expf(-omp[144 + g*9 + k]));
      float yp = (float)(y + ph - 1) + dy;
      float xp = (float)(x0 + i + kk - 1) + dx;
      float yf = floorf(yp), xf = floorf(xp);
      float wy = yp - yf, wx = xp - xf;
      int iy = (int)yf, ix = (int)xf;
      float wA = (1.f-wy)*(1.f-wx), wB = (1.f-wy)*wx, wC = wy*(1.f-wx), wD = wy*wx;
      bool y0ok = (unsigned)iy < 64u, y1ok = (unsigned)(iy+1) < 64u;
      bool x0ok = (unsigned)ix < 64u, x1ok = (unsigned)(ix+1) < 64u;
      if (!(y0ok && x0ok)) wA = 0.f;
      if (!(y0ok && x1ok)) wB = 0.f;
      if (!(y1ok && x0ok)) wC = 0.f;
      if (!(y1ok && x1ok)) wD = 0.f;
      int y0c = min(max(iy, 0), 63), y1c = min(max(iy + 1, 0), 63);
      int x0c = min(max(ix, 0), 63), x1c = min(max(ix + 1, 0), 63);
      int cofs = g*8 + lane8;
      float4 l00 = cb4[(y0c*64 + x0c)*64 + cofs];
      float4 l01 = cb4[(y0c*64 + x1c)*64 + cofs];
      float4 l10 = cb4[(y1c*64 + x0c)*64 + cofs];
      float4 l11 = cb4[(y1c*64 + x1c)*64 + cofs];
      int col = i*VST + kk*256 + g*32 + lane8*4;
      valb[col+0] = f2b((wA*l00.x + wB*l01.x + wC*l10.x + wD*l11.x) * mv);
      valb[col+1] = f2b((wA*l00.y + wB*l01.y + wC*l10.y + wD*l11.y) * mv);
      valb[col+2] = f2b((wA*l00.z + wB*l01.z + wC*l10.z + wD*l11.z) * mv);
      valb[col+3] = f2b((wA*l00.w + wB*l01.w + wC*l10.w + wD*l11.w) * mv);
    }
    __syncthreads();
    for (int ks = 0; ks < 24; ++ks){
      bf16x8 a = *(const bf16x8*)&valb[arow*VST + ks*32 + aquad*8];
      const bf16x8* wp = W8 + ((size_t)((ph*24 + ks)*16 + wave*4))*64 + lane;
#pragma unroll
      for (int t = 0; t < 4; ++t)
        acc[t] = MFMA16(a, wp[t*64], acc[t]);
    }
  }
#pragma unroll
  for (int t = 0; t < 4; ++t){
    int f = wave*64 + t*16 + (lane & 15);
    float bias = db[f];
#pragma unroll
    for (int r = 0; r < 4; ++r){
      int m = m0 + aquad*4 + r;
      out[(size_t)m*256 + f] = fmaxf(acc[t][r] + bias, 0.f) + fcal[(size_t)m*256 + f];
    }
  }
}

extern "C" void kernel_launch(void* const* d_in, const int* in_sizes, int n_in,
                              void* d_out, int out_size, void* d_ws, size_t ws_size,
                              hipStream_t stream){
  const float* fine     = (const float*)d_in[0];
  const float* coarse   = (const float*)d_in[1];
  const float* attend_w = (const float*)d_in[2];
  const float* select_w = (const float*)d_in[3];
  const float* offset_w = (const float*)d_in[4];
  const float* om_w     = (const float*)d_in[5];
  const float* om_b     = (const float*)d_in[6];
  const float* dcn_w    = (const float*)d_in[7];
  const float* dcn_b    = (const float*)d_in[8];
  float* out = (float*)d_out;
  float* ws  = (float*)d_ws;

  float* mean = ws + OFS_MEAN;
  float* gate = ws + OFS_GATE;
  float* wb   = ws + OFS_WB;
  float* cup  = ws + OFS_CUP;
  float* fcal = ws + OFS_FCAL;
  short* algb = (short*)(ws + OFS_ALGB);
  float* om   = ws + OFS_OM;
  short* dwb  = (short*)(ws + OFS_DWB);
  short* omwb = (short*)(ws + OFS_OMWB);

  hipLaunchKernelGGL(k_zero,     dim3(4),    dim3(256), 0, stream, mean);
  hipLaunchKernelGGL(k_cvt_dwb,  dim3(288),  dim3(256), 0, stream, dcn_w, dwb);
  hipLaunchKernelGGL(k_cvt_omwb, dim3(576),  dim3(256), 0, stream, om_w, omwb);
  hipLaunchKernelGGL(k_gap,      dim3(32),   dim3(256), 0, stream, fine, mean);
  hipLaunchKernelGGL(k_attn,     dim3(4),    dim3(256), 0, stream, mean, attend_w, gate);
  hipLaunchKernelGGL(k_foldw,    dim3(1024), dim3(256), 0, stream, gate, select_w, wb);
  hipLaunchKernelGGL(k_up,       dim3(4096), dim3(256), 0, stream, coarse, cup);
  hipLaunchKernelGGL(k_fcal,     dim3(1024), dim3(256), 0, stream, fine, wb, fcal);
  hipLaunchKernelGGL(k_align,    dim3(1024), dim3(256), 0, stream, fcal, cup, offset_w, algb);
  hipLaunchKernelGGL(k_om,       dim3(512),  dim3(256), 0, stream, algb, omwb, om_b, om);
  hipLaunchKernelGGL(k_dcn,      dim3(1024), dim3(256), 0, stream, cup, om, dwb, dcn_b, fcal, out);
  (void)in_sizes; (void)n_in; (void)out_size; (void)ws_size;
}

// Round 6
// 332.887 us; speedup vs baseline: 7.1570x; 1.3658x over previous
//
#include <hip/hip_runtime.h>
#include <math.h>

// B=4, H=W=64, C=256, DG=8, K=3, cpg=32; coarse: [4,32,32,256]

typedef __attribute__((ext_vector_type(8))) short bf16x8;
typedef __attribute__((ext_vector_type(4))) short bf16x4;
typedef __attribute__((ext_vector_type(4))) float f32x4;
#define MFMA16(a,b,c) __builtin_amdgcn_mfma_f32_16x16x32_bf16(a,b,c,0,0,0)

__device__ inline short f2b(float x){
  union { float f; unsigned u; } v; v.f = x;
  unsigned r = v.u + 0x7FFFu + ((v.u >> 16) & 1u);
  return (short)(r >> 16);
}

// workspace layout (float offsets)
#define OFS_MEAN  0u
#define OFS_GATE  1024u
#define OFS_CUP   264192u
#define OFS_FCAL  4458496u
#define OFS_ALGB  8652800u     // bf16 [16384][512]
#define OFS_OM    12847104u    // f32  [16384][216]
#define OFS_DWB   16386048u    // bf16 frag [72][16][64][8]
#define OFS_OMWB  16680960u    // bf16 frag [144][16][64][8]
#define OFS_WBB   17270784u    // bf16 frag [4][8][16][64][8]
#define OFS_OWB   17401856u    // bf16 frag [16][32][64][8]

__global__ void k_zero(float* __restrict__ p){
  p[blockIdx.x*256 + threadIdx.x] = 0.f;
}

__global__ void k_gap(const float* __restrict__ fine, float* __restrict__ mean){
  int b = blockIdx.x >> 3, chunk = blockIdx.x & 7, c = threadIdx.x;
  const float* p = fine + ((size_t)(b*4096 + chunk*512))*256 + c;
  float s = 0.f;
  for (int i = 0; i < 512; ++i) s += p[i*256];
  atomicAdd(&mean[b*256 + c], s);
}

__global__ void k_attn(const float* __restrict__ mean, const float* __restrict__ aw,
                       float* __restrict__ gate){
  __shared__ float m[256];
  int b = blockIdx.x, f = threadIdx.x;
  m[f] = mean[b*256 + f] * (1.f/4096.f);
  __syncthreads();
  float s = 0.f;
  for (int c = 0; c < 256; ++c) s += m[c] * aw[c*256 + f];
  gate[b*256 + f] = 1.f + 1.f/(1.f + expf(-s));
}

// Wb frags: wbb[((b*8+ksg)*16+nt)*64+l][8]; w = gate[b,k]*sw[k,n]
__global__ void k_foldw_frag(const float* __restrict__ gate, const float* __restrict__ sw,
                             short* __restrict__ wbb){
  int t = blockIdx.x*256 + threadIdx.x;          // 32768
  int l = t & 63, nt = (t >> 6) & 15, ksg = (t >> 10) & 7, b = t >> 13;
  int n = nt*16 + (l & 15);
  int kb = ksg*32 + (l >> 4)*8;
  bf16x8 o;
#pragma unroll
  for (int j = 0; j < 8; ++j){
    int k = kb + j;
    o[j] = f2b(gate[b*256 + k] * sw[(size_t)k*256 + n]);
  }
  ((bf16x8*)wbb)[t] = o;
}

// offset_w frags, 2x folded for k>=256: owb[(ksg*32+nt)*64+l][8]
__global__ void k_cvt_owb(const float* __restrict__ ow, short* __restrict__ owb){
  int t = blockIdx.x*256 + threadIdx.x;          // 32768
  int l = t & 63, nt = (t >> 6) & 31, ksg = t >> 11;
  int n = nt*16 + (l & 15);
  int kb = ksg*32 + (l >> 4)*8;
  float sc = (kb >= 256) ? 2.f : 1.f;
  bf16x8 o;
#pragma unroll
  for (int j = 0; j < 8; ++j) o[j] = f2b(sc * ow[(size_t)(kb + j)*512 + n]);
  ((bf16x8*)owb)[t] = o;
}

__global__ void k_up(const float* __restrict__ coarse, float* __restrict__ cup){
  int idx = blockIdx.x*256 + threadIdx.x;
  int c4 = idx & 63, x = (idx >> 6) & 63, y = (idx >> 12) & 63, b = idx >> 18;
  float fy = 0.5f*y - 0.25f, fx = 0.5f*x - 0.25f;
  float yf = floorf(fy), xf = floorf(fx);
  float wy = fy - yf, wx = fx - xf;
  int r0 = max(0, min(31, (int)yf)), r1 = max(0, min(31, (int)yf + 1));
  int c0 = max(0, min(31, (int)xf)), c1 = max(0, min(31, (int)xf + 1));
  const float4* src = (const float4*)coarse;
  float4 v00 = src[((b*32 + r0)*32 + c0)*64 + c4];
  float4 v01 = src[((b*32 + r0)*32 + c1)*64 + c4];
  float4 v10 = src[((b*32 + r1)*32 + c0)*64 + c4];
  float4 v11 = src[((b*32 + r1)*32 + c1)*64 + c4];
  float w00 = (1.f-wy)*(1.f-wx), w01 = (1.f-wy)*wx, w10 = wy*(1.f-wx), w11 = wy*wx;
  float4 o;
  o.x = v00.x*w00 + v01.x*w01 + v10.x*w10 + v11.x*w11;
  o.y = v00.y*w00 + v01.y*w01 + v10.y*w10 + v11.y*w11;
  o.z = v00.z*w00 + v01.z*w01 + v10.z*w10 + v11.z*w11;
  o.w = v00.w*w00 + v01.w*w01 + v10.w*w10 + v11.w*w11;
  ((float4*)cup)[idx] = o;
}

// fine_cal = fine @ Wb[b] via MFMA; M-tile 32, stage fine->bf16 LDS
#define FST 264
__global__ __launch_bounds__(256) void k_fcal(const float* __restrict__ fine,
                                              const short* __restrict__ wbb,
                                              float* __restrict__ fcal){
  __shared__ short ab[32*FST];
  int m0 = blockIdx.x*32, b = m0 >> 12;
  int tid = threadIdx.x, lane = tid & 63, wave = tid >> 6;
  int arow = lane & 15, aquad = lane >> 4;
  const float4* F4 = (const float4*)(fine + (size_t)m0*256);
  for (int it = 0; it < 8; ++it){
    int idx = it*256 + tid;                      // 0..2047
    int row = idx >> 6, c4 = idx & 63;
    float4 v = F4[row*64 + c4];
    bf16x4 s4 = { f2b(v.x), f2b(v.y), f2b(v.z), f2b(v.w) };
    *(bf16x4*)&ab[row*FST + c4*4] = s4;
  }
  __syncthreads();
  f32x4 acc[2][4];
#pragma unroll
  for (int s = 0; s < 2; ++s)
#pragma unroll
    for (int t = 0; t < 4; ++t) acc[s][t] = (f32x4){0.f,0.f,0.f,0.f};
  const bf16x8* W8 = (const bf16x8*)wbb;
  for (int ks = 0; ks < 8; ++ks){
    bf16x8 a0 = *(const bf16x8*)&ab[arow*FST + ks*32 + aquad*8];
    bf16x8 a1 = *(const bf16x8*)&ab[(16 + arow)*FST + ks*32 + aquad*8];
    const bf16x8* wp = W8 + ((size_t)((b*8 + ks)*16 + wave*4))*64 + lane;
#pragma unroll
    for (int t = 0; t < 4; ++t){
      bf16x8 bw = wp[t*64];
      acc[0][t] = MFMA16(a0, bw, acc[0][t]);
      acc[1][t] = MFMA16(a1, bw, acc[1][t]);
    }
  }
#pragma unroll
  for (int t = 0; t < 4; ++t){
    int f = wave*64 + t*16 + (lane & 15);
#pragma unroll
    for (int s = 0; s < 2; ++s)
#pragma unroll
      for (int r = 0; r < 4; ++r){
        int m = m0 + s*16 + aquad*4 + r;
        fcal[(size_t)m*256 + f] = acc[s][t][r];
      }
  }
}

// align = concat(fcal, cup) @ owb (2x folded) via MFMA; inline fp32->bf16 A-frags
__global__ __launch_bounds__(256) void k_align(const float* __restrict__ fcal,
                                               const float* __restrict__ cup,
                                               const short* __restrict__ owb,
                                               short* __restrict__ algb){
  int m0 = blockIdx.x*32;
  int tid = threadIdx.x, lane = tid & 63, wave = tid >> 6;
  int arow = lane & 15, aquad = lane >> 4;
  f32x4 acc[2][8];
#pragma unroll
  for (int s = 0; s < 2; ++s)
#pragma unroll
    for (int t = 0; t < 8; ++t) acc[s][t] = (f32x4){0.f,0.f,0.f,0.f};
  const bf16x8* OW8 = (const bf16x8*)owb;
  for (int ks = 0; ks < 16; ++ks){
    const float* src = (ks < 8) ? fcal : cup;
    int ko = (ks & 7)*32 + aquad*8;
    const float4* ap0 = (const float4*)(src + (size_t)(m0 + arow)*256 + ko);
    const float4* ap1 = (const float4*)(src + (size_t)(m0 + 16 + arow)*256 + ko);
    float4 f00 = ap0[0], f01 = ap0[1];
    float4 f10 = ap1[0], f11 = ap1[1];
    bf16x8 a0 = { f2b(f00.x), f2b(f00.y), f2b(f00.z), f2b(f00.w),
                  f2b(f01.x), f2b(f01.y), f2b(f01.z), f2b(f01.w) };
    bf16x8 a1 = { f2b(f10.x), f2b(f10.y), f2b(f10.z), f2b(f10.w),
                  f2b(f11.x), f2b(f11.y), f2b(f11.z), f2b(f11.w) };
    const bf16x8* wp = OW8 + ((size_t)(ks*32 + wave*8))*64 + lane;
#pragma unroll
    for (int t = 0; t < 8; ++t){
      bf16x8 bw = wp[t*64];
      acc[0][t] = MFMA16(a0, bw, acc[0][t]);
      acc[1][t] = MFMA16(a1, bw, acc[1][t]);
    }
  }
#pragma unroll
  for (int t = 0; t < 8; ++t){
    int n = wave*128 + t*16 + (lane & 15);
#pragma unroll
    for (int s = 0; s < 2; ++s)
#pragma unroll
      for (int r = 0; r < 4; ++r){
        int m = m0 + s*16 + aquad*4 + r;
        algb[(size_t)m*512 + n] = f2b(acc[s][t][r]);
      }
  }
}

// dcn_w -> B-frag bf16
__global__ void k_cvt_dwb(const float* __restrict__ dw, short* __restrict__ dwb){
  int t = blockIdx.x*256 + threadIdx.x;          // 73728
  int l = t & 63, nt = (t >> 6) & 15, ksg = t >> 10;
  int n = nt*16 + (l & 15);
  int kb = ksg*32 + (l >> 4)*8;
  bf16x8 o;
#pragma unroll
  for (int j = 0; j < 8; ++j) o[j] = f2b(dw[(size_t)(kb + j)*256 + n]);
  ((bf16x8*)dwb)[t] = o;
}

// om_w -> B-frag bf16, N padded 216->256
__global__ void k_cvt_omwb(const float* __restrict__ omw, short* __restrict__ omwb){
  int t = blockIdx.x*256 + threadIdx.x;          // 147456
  int l = t & 63, nt = (t >> 6) & 15, ksg = t >> 10;
  int n = nt*16 + (l & 15);
  int kb = ksg*32 + (l >> 4)*8;
  bf16x8 o;
#pragma unroll
  for (int j = 0; j < 8; ++j)
    o[j] = (n < 216) ? f2b(omw[(size_t)(kb + j)*216 + n]) : (short)0;
  ((bf16x8*)omwb)[t] = o;
}

// om conv3x3 as MFMA implicit GEMM. M-tile 32, N padded 256, phase per ky.
#define XST 520
__global__ __launch_bounds__(256) void k_om(const short* __restrict__ algb,
                                            const short* __restrict__ omwb,
                                            const float* __restrict__ omb,
                                            float* __restrict__ om){
  __shared__ short xbuf[34*XST];
  int m0 = blockIdx.x*32;
  int b = m0 >> 12, y = (m0 & 4095) >> 6, x0 = m0 & 63;
  int tid = threadIdx.x;
  int lane = tid & 63, wave = tid >> 6;
  int arow = lane & 15, aquad = lane >> 4;
  f32x4 acc[2][4];
#pragma unroll
  for (int s = 0; s < 2; ++s)
#pragma unroll
    for (int t = 0; t < 4; ++t) acc[s][t] = (f32x4){0.f,0.f,0.f,0.f};
  const bf16x8* W8 = (const bf16x8*)omwb;
  for (int ky = 0; ky < 3; ++ky){
    int yy = y + ky - 1;
    if ((unsigned)yy >= 64u) continue;           // block-uniform
    __syncthreads();
    const short* srow = algb + (size_t)((b*64 + yy)*64)*512;
    for (int it = 0; it < 9; ++it){
      int idx = it*256 + tid;
      if (idx < 2176){
        int xx = idx >> 6, l8 = idx & 63;
        int gx = x0 - 1 + xx;
        bf16x8 v = (bf16x8){0,0,0,0,0,0,0,0};
        if ((unsigned)gx < 64u) v = *(const bf16x8*)(srow + (size_t)gx*512 + l8*8);
        *(bf16x8*)&xbuf[xx*XST + l8*8] = v;
      }
    }
    __syncthreads();
    for (int ks = 0; ks < 48; ++ks){
      int kl = ks*32 + aquad*8;
      int kx = kl >> 9, cc = kl & 511;
      bf16x8 a0 = *(const bf16x8*)&xbuf[(arow + kx)*XST + cc];
      bf16x8 a1 = *(const bf16x8*)&xbuf[(16 + arow + kx)*XST + cc];
      const bf16x8* wp = W8 + ((size_t)((ky*48 + ks)*16 + wave*4))*64 + lane;
#pragma unroll
      for (int t = 0; t < 4; ++t){
        bf16x8 bw = wp[t*64];
        acc[0][t] = MFMA16(a0, bw, acc[0][t]);
        acc[1][t] = MFMA16(a1, bw, acc[1][t]);
      }
    }
  }
#pragma unroll
  for (int t = 0; t < 4; ++t){
    int f = wave*64 + t*16 + (lane & 15);
    if (f < 216){
      float bias = omb[f];
#pragma unroll
      for (int s = 0; s < 2; ++s)
#pragma unroll
        for (int r = 0; r < 4; ++r){
          int m = m0 + s*16 + (lane >> 4)*4 + r;
          om[(size_t)m*216 + f] = acc[s][t][r] + bias;
        }
    }
  }
}

// DCNv2: staging by 8-lane units (params in-register, float4 channel gather),
// then MFMA GEMM. M-tile 16.
#define VST 776
__global__ __launch_bounds__(256) void k_dcn(const float* __restrict__ cup,
                                             const float* __restrict__ om,
                                             const short* __restrict__ dwb,
                                             const float* __restrict__ db,
                                             const float* __restrict__ fcal,
                                             float* __restrict__ out){
  __shared__ short valb[16*VST];   // 24832 B
  int m0 = blockIdx.x*16;
  int b = m0 >> 12, y = (m0 & 4095) >> 6, x0 = m0 & 63;
  int tid = threadIdx.x;
  int lane = tid & 63, wave = tid >> 6;
  int unit = tid >> 3, lane8 = tid & 7;    // 32 units x 8 lanes
  int arow = lane & 15, aquad = lane >> 4;
  f32x4 acc[4];
#pragma unroll
  for (int t = 0; t < 4; ++t) acc[t] = (f32x4){0.f,0.f,0.f,0.f};
  const float4* cb4 = (const float4*)(cup + (size_t)b*4096*256);
  const bf16x8* W8 = (const bf16x8*)dwb;

  for (int ph = 0; ph < 3; ++ph){
    __syncthreads();
    for (int j = 0; j < 12; ++j){
      int u = j*32 + unit;
      int i = u / 24; int r = u - i*24; int g = r / 3; int kk = r - g*3;
      const float* omp = om + (size_t)(m0 + i)*216;
      int k = ph*3 + kk;
      float dy = omp[(g*9 + k)*2 + 0];
      float dx = omp[(g*9 + k)*2 + 1];
      float mv = 1.f / (1.f + expf(-omp[144 + g*9 + k]));
      float yp = (float)(y + ph - 1) + dy;
      float xp = (float)(x0 + i + kk - 1) + dx;
      float yf = floorf(yp), xf = floorf(xp);
      float wy = yp - yf, wx = xp - xf;
      int iy = (int)yf, ix = (int)xf;
      float wA = (1.f-wy)*(1.f-wx), wB = (1.f-wy)*wx, wC = wy*(1.f-wx), wD = wy*wx;
      bool y0ok = (unsigned)iy < 64u, y1ok = (unsigned)(iy+1) < 64u;
      bool x0ok = (unsigned)ix < 64u, x1ok = (unsigned)(ix+1) < 64u;
      if (!(y0ok && x0ok)) wA = 0.f;
      if (!(y0ok && x1ok)) wB = 0.f;
      if (!(y1ok && x0ok)) wC = 0.f;
      if (!(y1ok && x1ok)) wD = 0.f;
      int y0c = min(max(iy, 0), 63), y1c = min(max(iy + 1, 0), 63);
      int x0c = min(max(ix, 0), 63), x1c = min(max(ix + 1, 0), 63);
      int cofs = g*8 + lane8;
      float4 l00 = cb4[(y0c*64 + x0c)*64 + cofs];
      float4 l01 = cb4[(y0c*64 + x1c)*64 + cofs];
      float4 l10 = cb4[(y1c*64 + x0c)*64 + cofs];
      float4 l11 = cb4[(y1c*64 + x1c)*64 + cofs];
      int col = i*VST + kk*256 + g*32 + lane8*4;
      valb[col+0] = f2b((wA*l00.x + wB*l01.x + wC*l10.x + wD*l11.x) * mv);
      valb[col+1] = f2b((wA*l00.y + wB*l01.y + wC*l10.y + wD*l11.y) * mv);
      valb[col+2] = f2b((wA*l00.z + wB*l01.z + wC*l10.z + wD*l11.z) * mv);
      valb[col+3] = f2b((wA*l00.w + wB*l01.w + wC*l10.w + wD*l11.w) * mv);
    }
    __syncthreads();
    for (int ks = 0; ks < 24; ++ks){
      bf16x8 a = *(const bf16x8*)&valb[arow*VST + ks*32 + aquad*8];
      const bf16x8* wp = W8 + ((size_t)((ph*24 + ks)*16 + wave*4))*64 + lane;
#pragma unroll
      for (int t = 0; t < 4; ++t)
        acc[t] = MFMA16(a, wp[t*64], acc[t]);
    }
  }
#pragma unroll
  for (int t = 0; t < 4; ++t){
    int f = wave*64 + t*16 + (lane & 15);
    float bias = db[f];
#pragma unroll
    for (int r = 0; r < 4; ++r){
      int m = m0 + aquad*4 + r;
      out[(size_t)m*256 + f] = fmaxf(acc[t][r] + bias, 0.f) + fcal[(size_t)m*256 + f];
    }
  }
}

extern "C" void kernel_launch(void* const* d_in, const int* in_sizes, int n_in,
                              void* d_out, int out_size, void* d_ws, size_t ws_size,
                              hipStream_t stream){
  const float* fine     = (const float*)d_in[0];
  const float* coarse   = (const float*)d_in[1];
  const float* attend_w = (const float*)d_in[2];
  const float* select_w = (const float*)d_in[3];
  const float* offset_w = (const float*)d_in[4];
  const float* om_w     = (const float*)d_in[5];
  const float* om_b     = (const float*)d_in[6];
  const float* dcn_w    = (const float*)d_in[7];
  const float* dcn_b    = (const float*)d_in[8];
  float* out = (float*)d_out;
  float* ws  = (float*)d_ws;

  float* mean = ws + OFS_MEAN;
  float* gate = ws + OFS_GATE;
  float* cup  = ws + OFS_CUP;
  float* fcal = ws + OFS_FCAL;
  short* algb = (short*)(ws + OFS_ALGB);
  float* om   = ws + OFS_OM;
  short* dwb  = (short*)(ws + OFS_DWB);
  short* omwb = (short*)(ws + OFS_OMWB);
  short* wbb  = (short*)(ws + OFS_WBB);
  short* owb  = (short*)(ws + OFS_OWB);

  hipLaunchKernelGGL(k_zero,       dim3(4),    dim3(256), 0, stream, mean);
  hipLaunchKernelGGL(k_cvt_dwb,    dim3(288),  dim3(256), 0, stream, dcn_w, dwb);
  hipLaunchKernelGGL(k_cvt_omwb,   dim3(576),  dim3(256), 0, stream, om_w, omwb);
  hipLaunchKernelGGL(k_cvt_owb,    dim3(128),  dim3(256), 0, stream, offset_w, owb);
  hipLaunchKernelGGL(k_gap,        dim3(32),   dim3(256), 0, stream, fine, mean);
  hipLaunchKernelGGL(k_attn,       dim3(4),    dim3(256), 0, stream, mean, attend_w, gate);
  hipLaunchKernelGGL(k_foldw_frag, dim3(128),  dim3(256), 0, stream, gate, select_w, wbb);
  hipLaunchKernelGGL(k_up,         dim3(4096), dim3(256), 0, stream, coarse, cup);
  hipLaunchKernelGGL(k_fcal,       dim3(512),  dim3(256), 0, stream, fine, wbb, fcal);
  hipLaunchKernelGGL(k_align,      dim3(512),  dim3(256), 0, stream, fcal, cup, owb, algb);
  hipLaunchKernelGGL(k_om,         dim3(512),  dim3(256), 0, stream, algb, omwb, om_b, om);
  hipLaunchKernelGGL(k_dcn,        dim3(1024), dim3(256), 0, stream, cup, om, dwb, dcn_b, fcal, out);
  (void)in_sizes; (void)n_in; (void)out_size; (void)ws_size;
}